// Round 1
// baseline (858.928 us; speedup 1.0000x reference)
//
#include <hip/hip_runtime.h>
#include <math.h>

// Problem constants (from reference)
#define N_TOK 8192
#define DIM   4096
#define NEXP  64
#define CAP   160                        // ceil(1.25*8192/64)
#define NEC   (83886080ULL)              // N_TOK*NEXP*CAP
#define OFF_CW    (83886080ULL)
#define OFF_PROBS (167772160ULL)
#define OFF_LOSS  (168296448ULL)         // OFF_PROBS + N_TOK*NEXP
#define NA    16384                      // N_TOK * K

// ---------------- wave (64-lane) reductions ----------------
__device__ __forceinline__ float wave_max64(float v) {
    for (int m = 1; m < 64; m <<= 1) v = fmaxf(v, __shfl_xor(v, m, 64));
    return v;
}
__device__ __forceinline__ float wave_sum64(float v) {
    for (int m = 1; m < 64; m <<= 1) v += __shfl_xor(v, m, 64);
    return v;
}
// argmax with tie-break to LOWEST index (matches lax.top_k stability)
__device__ __forceinline__ void wave_argmax64(float& v, int& i) {
    for (int m = 1; m < 64; m <<= 1) {
        float ov = __shfl_xor(v, m, 64);
        int   oi = __shfl_xor(i, m, 64);
        if (ov > v || (ov == v && oi < i)) { v = ov; i = oi; }
    }
}

// ---------------- K1: logits GEMM (fp32, split over D) ----------------
// grid (128, S), block 256. Block computes 64 tokens x 64 experts partial
// dot over its D-slice. 4x4 register tile per thread, LDS staging.
__global__ __launch_bounds__(256) void k_gemm(const float* __restrict__ x,
                                              const float* __restrict__ gw,
                                              float* __restrict__ part, int dps) {
    __shared__ float xs[64][68];   // +4 pad: breaks pow2 bank stride, keeps 16B align
    __shared__ float wsh[64][68];
    const int tb = blockIdx.x * 64;
    const int d_begin = blockIdx.y * dps;
    const int t  = threadIdx.x;
    const int tx = t & 15, ty = t >> 4;
    float acc[4][4] = {};
    for (int ci = 0; ci < dps / 64; ++ci) {
        const int d0 = d_begin + ci * 64;
        for (int it = 0; it < 4; ++it) {
            int idx = t + 256 * it;        // 0..1023
            int row = idx >> 4;            // 0..63
            int d4  = idx & 15;
            *(float4*)(&xs[row][4 * d4]) =
                *(const float4*)(x + (size_t)(tb + row) * DIM + d0 + 4 * d4);
            *(float4*)(&wsh[row][4 * d4]) =
                *(const float4*)(gw + (size_t)row * DIM + d0 + 4 * d4);
        }
        __syncthreads();
        for (int d4 = 0; d4 < 16; ++d4) {
            float4 xa[4], wb[4];
            for (int i = 0; i < 4; ++i) xa[i] = *(const float4*)(&xs[ty + 16 * i][4 * d4]);
            for (int j = 0; j < 4; ++j) wb[j] = *(const float4*)(&wsh[tx + 16 * j][4 * d4]);
            for (int i = 0; i < 4; ++i)
                for (int j = 0; j < 4; ++j) {
                    acc[i][j] = fmaf(xa[i].x, wb[j].x, acc[i][j]);
                    acc[i][j] = fmaf(xa[i].y, wb[j].y, acc[i][j]);
                    acc[i][j] = fmaf(xa[i].z, wb[j].z, acc[i][j]);
                    acc[i][j] = fmaf(xa[i].w, wb[j].w, acc[i][j]);
                }
        }
        __syncthreads();
    }
    for (int i = 0; i < 4; ++i)
        for (int j = 0; j < 4; ++j)
            part[(size_t)blockIdx.y * N_TOK * NEXP +
                 (size_t)(tb + ty + 16 * i) * NEXP + (tx + 16 * j)] = acc[i][j];
}

// ---------------- K2: softmax + top-2 per token (wave per token) ----------------
__global__ __launch_bounds__(256) void k_router(const float* __restrict__ part, int S,
                                                float* __restrict__ probs_out,
                                                int* __restrict__ rec_e,
                                                float* __restrict__ rec_w) {
    const int tok  = blockIdx.x * 4 + (threadIdx.x >> 6);
    const int lane = threadIdx.x & 63;
    float l = 0.f;
    for (int s = 0; s < S; ++s)
        l += part[(size_t)s * N_TOK * NEXP + (size_t)tok * NEXP + lane];
    const float m  = wave_max64(l);
    const float ex = expf(l - m);
    const float sm = wave_sum64(ex);
    const float p  = ex / sm;
    probs_out[(size_t)tok * NEXP + lane] = p;
    // top-1
    float v1 = p; int i1 = lane;
    wave_argmax64(v1, i1);
    // top-2 (exclude i1; probs >= 0 so -1 is a safe -inf)
    float v2 = (lane == i1) ? -1.f : p; int i2 = lane;
    wave_argmax64(v2, i2);
    if (lane == 0) {
        const float denom = v1 + v2;
        rec_e[2 * tok]     = i1;
        rec_e[2 * tok + 1] = i2;
        rec_w[2 * tok]     = v1 / denom;
        rec_w[2 * tok + 1] = v2 / denom;
    }
}

// ---------------- K2b: p = mean probs per expert ----------------
__global__ __launch_bounds__(256) void k_preduce(const float* __restrict__ probs,
                                                 float* __restrict__ p_sum) {
    __shared__ float sh[256];
    const int e = threadIdx.x & 63, tg = threadIdx.x >> 6;
    const int tok0 = blockIdx.x * 1024;
    float a = 0.f;
    for (int k = 0; k < 256; ++k)
        a += probs[(size_t)(tok0 + tg + 4 * k) * NEXP + e];
    sh[threadIdx.x] = a;
    __syncthreads();
    if (threadIdx.x < 64) {
        float s = sh[threadIdx.x] + sh[64 + threadIdx.x] +
                  sh[128 + threadIdx.x] + sh[192 + threadIdx.x];
        atomicAdd(&p_sum[threadIdx.x], s);
    }
}

// ---------------- K3a: per-chunk expert histogram (chunk = 256 assignments) ----------------
__global__ void k_count(const int* __restrict__ rec_e, int* __restrict__ chunk_cnt) {
    __shared__ int cnt[64];
    const int lane = threadIdx.x, b = blockIdx.x;
    cnt[lane] = 0;
    __syncthreads();
    for (int r = 0; r < 4; ++r)
        atomicAdd(&cnt[rec_e[b * 256 + r * 64 + lane]], 1);
    __syncthreads();
    chunk_cnt[b * 64 + lane] = cnt[lane];
}

// ---------------- K3b: exclusive scan of chunk counts per expert + loss ----------------
__global__ void k_scan(const int* __restrict__ chunk_cnt, int* __restrict__ chunk_base,
                       const float* __restrict__ p_sum, float* __restrict__ loss_out) {
    const int e = threadIdx.x;   // 64 threads = 1 wave
    int run = 0;
    for (int b = 0; b < 64; ++b) {
        chunk_base[b * 64 + e] = run;
        run += chunk_cnt[b * 64 + e];
    }
    // load-balance loss: 0.01 * 64 * sum_e f_e * p_e   (f counts ALL top-k picks)
    float term = ((float)run / (float)NA) * (p_sum[e] / (float)N_TOK);
    term = wave_sum64(term);
    if (e == 0) loss_out[0] = 0.01f * 64.f * term;
}

// ---------------- K3c: ordered slot assignment within each chunk ----------------
__global__ void k_slots(const int* __restrict__ rec_e, const int* __restrict__ chunk_base,
                        int* __restrict__ rec_s) {
    __shared__ int cnt[64];
    __shared__ int she[64];
    const int lane = threadIdx.x, b = blockIdx.x;
    cnt[lane] = chunk_base[b * 64 + lane];
    __syncthreads();
    for (int r = 0; r < 4; ++r) {
        const int i = b * 256 + r * 64 + lane;
        const int e = rec_e[i];
        she[lane] = e;
        __syncthreads();
        int prior = 0, total = 0;
        for (int j = 0; j < 64; ++j) {
            int mt = (she[j] == e);
            total += mt;
            prior += (j < lane) ? mt : 0;
        }
        const int sb   = cnt[e];
        const int slot = sb + prior;
        rec_s[i] = (slot < CAP) ? slot : -1;
        __syncthreads();
        if (prior == 0) cnt[e] = sb + total;   // first occurrence per expert updates
        __syncthreads();
    }
}

// ---------------- K4: streaming writer of dispatch_mask + combine_weights ----------------
// One block per token: writes its full 64x160 slab of both arrays, float4, coalesced.
__global__ __launch_bounds__(256) void k_write(const int* __restrict__ rec_e,
                                               const int* __restrict__ rec_s,
                                               const float* __restrict__ rec_w,
                                               float* __restrict__ out) {
    const int tok = blockIdx.x;
    const int e1 = rec_e[2 * tok], e2 = rec_e[2 * tok + 1];
    const int s1 = rec_s[2 * tok], s2 = rec_s[2 * tok + 1];
    const float w1 = rec_w[2 * tok], w2 = rec_w[2 * tok + 1];
    const int p1 = (s1 >= 0) ? e1 * CAP + s1 : -1;
    const int p2 = (s2 >= 0) ? e2 * CAP + s2 : -1;
    const int o1 = (p1 >= 0) ? (p1 >> 2) : -1, c1 = p1 & 3;
    const int o2 = (p2 >= 0) ? (p2 >> 2) : -1, c2 = p2 & 3;
    float* dm = out + (size_t)tok * (NEXP * CAP);
    float* cw = out + OFF_CW + (size_t)tok * (NEXP * CAP);
    for (int it = 0; it < 10; ++it) {
        const int o = it * 256 + threadIdx.x;   // float4 index in [0, 2560)
        float4 d = {0.f, 0.f, 0.f, 0.f};
        float4 c = {0.f, 0.f, 0.f, 0.f};
        if (o == o1) { ((float*)&d)[c1] = 1.f; ((float*)&c)[c1] = w1; }
        if (o == o2) { ((float*)&d)[c2] = 1.f; ((float*)&c)[c2] = w2; }
        *(float4*)(dm + 4 * o) = d;
        *(float4*)(cw + 4 * o) = c;
    }
}

extern "C" void kernel_launch(void* const* d_in, const int* in_sizes, int n_in,
                              void* d_out, int out_size, void* d_ws, size_t ws_size,
                              hipStream_t stream) {
    const float* x  = (const float*)d_in[0];
    const float* gw = (const float*)d_in[1];
    float* out = (float*)d_out;

    // workspace layout (choose D-split by available scratch)
    int S = 4;
    size_t need = ((size_t)S * N_TOK * NEXP + 3 * NA + 2 * 4096 + 64) * 4;
    if (ws_size < need) S = 1;
    char* w = (char*)d_ws;
    float* part      = (float*)w;
    int*   rec_e     = (int*)(w + (size_t)S * N_TOK * NEXP * 4);
    float* rec_w     = (float*)((char*)rec_e + NA * 4);
    int*   rec_s     = (int*)((char*)rec_w + NA * 4);
    int*   chunk_cnt = (int*)((char*)rec_s + NA * 4);
    int*   chunk_base= (int*)((char*)chunk_cnt + 4096 * 4);
    float* p_sum     = (float*)((char*)chunk_base + 4096 * 4);

    hipMemsetAsync(p_sum, 0, 64 * 4, stream);

    dim3 g1(128, S);
    k_gemm<<<g1, 256, 0, stream>>>(x, gw, part, DIM / S);
    k_router<<<2048, 256, 0, stream>>>(part, S, out + OFF_PROBS, rec_e, rec_w);
    k_preduce<<<8, 256, 0, stream>>>(out + OFF_PROBS, p_sum);
    k_count<<<64, 64, 0, stream>>>(rec_e, chunk_cnt);
    k_scan<<<1, 64, 0, stream>>>(chunk_cnt, chunk_base, p_sum, out + OFF_LOSS);
    k_slots<<<64, 64, 0, stream>>>(rec_e, chunk_base, rec_s);
    k_write<<<8192, 256, 0, stream>>>(rec_e, rec_s, rec_w, out);
}